// Round 6
// baseline (45.495 us; speedup 1.0000x reference)
//
#include <hip/hip_runtime.h>

// Problem constants (match reference)
#define HH    128
#define WWID  128
#define CCH   3
#define PP    16
#define NIMG  64
#define NPROJ 512
#define NXCD  8
#define IMGS_PER_XCD (NIMG / NXCD)

#define TOTAL_ELEMS 25165824
#define SLICE_ELEMS (NPROJ * IMGS_PER_XCD * CCH * PP * PP)  // 3,145,728
#define SLICE_VEC8  (SLICE_ELEMS / 8)                       // 393,216
#define BLOCKS_PER_SLICE (SLICE_VEC8 / 256)                 // 1,536

typedef float f32x4 __attribute__((ext_vector_type(4)));

__global__ __launch_bounds__(256) void cut_patches_kernel(
    const float* __restrict__ imgs,
    const int*   __restrict__ pih,
    const int*   __restrict__ piw,
    float*       __restrict__ out_patches,
    float*       __restrict__ out_inds)
{
    int xcd = blockIdx.x & (NXCD - 1);
    int bid = blockIdx.x >> 3;
    int s   = bid * blockDim.x + threadIdx.x;   // 0 .. SLICE_VEC8-1

    int e = s << 3;                   // first element; thread covers 8 elems (half row)
    // decomposition (pw fastest): proj boundary = 6144 elems = 12 waves of 512,
    // so proj / w0 / t are wave-uniform (no divergent recombine).
    int pw  = e & 15;                 // 0 or 8
    int tmp = e >> 4;
    int ph  = tmp & 15;
    tmp >>= 4;
    int c   = tmp % 3;
    tmp    /= 3;
    int nl  = tmp & (IMGS_PER_XCD - 1);
    int proj = tmp >> 3;
    int n   = (xcd << 3) | nl;

    int h0 = pih[proj];
    int w0 = piw[proj];

    int hh = h0 + ph;
    if (hh >= HH) hh -= HH;

    // base float index of this image row (multiple of 128 -> chunk-aligned)
    int base = hh * WWID + c * (HH * WWID) + n * (CCH * HH * WWID);
    const f32x4* rowv = reinterpret_cast<const f32x4*>(imgs) + (base >> 2); // 32 chunks/row

    int cb = (w0 >> 2) + (pw >> 2);   // first source chunk (pre-wrap)
    int t  = w0 & 3;                  // wave-uniform misalignment

    // Aligned vec4 gathers + wave-uniform recombine (compile-time swizzles only).
    f32x4 A = rowv[cb & 31];
    f32x4 v0, v1;
    if (t == 0) {
        f32x4 B = rowv[(cb + 1) & 31];
        v0 = A; v1 = B;
    } else {
        f32x4 B = rowv[(cb + 1) & 31];
        f32x4 C = rowv[(cb + 2) & 31];
        if (t == 1) {
            v0 = (f32x4){A.y, A.z, A.w, B.x};
            v1 = (f32x4){B.y, B.z, B.w, C.x};
        } else if (t == 2) {
            v0 = (f32x4){A.z, A.w, B.x, B.y};
            v1 = (f32x4){B.z, B.w, C.x, C.y};
        } else {
            v0 = (f32x4){A.w, B.x, B.y, B.z};
            v1 = (f32x4){B.w, C.x, C.y, C.z};
        }
    }

    // linear indices (exact in f32: lin < 2^24)
    f32x4 i0, i1;
#pragma unroll
    for (int j = 0; j < 4; ++j) {
        int w = w0 + pw + j;
        if (w >= WWID) w -= WWID;
        i0[j] = (float)(base + w);
        int w2 = w0 + pw + 4 + j;
        if (w2 >= WWID) w2 -= WWID;
        i1[j] = (float)(base + w2);
    }

    // output vec index (global layout [proj][n][c][ph][pw])
    int oelem = (((proj * NIMG + n) * CCH + c) << 8) | (ph << 4) | pw;
    int ovec  = oelem >> 2;

    f32x4* op = reinterpret_cast<f32x4*>(out_patches);
    f32x4* oi = reinterpret_cast<f32x4*>(out_inds);
    op[ovec]     = v0;
    op[ovec + 1] = v1;
    oi[ovec]     = i0;
    oi[ovec + 1] = i1;
}

extern "C" void kernel_launch(void* const* d_in, const int* in_sizes, int n_in,
                              void* d_out, int out_size, void* d_ws, size_t ws_size,
                              hipStream_t stream) {
    const float* imgs = (const float*)d_in[0];
    const int*   pih  = (const int*)d_in[1];
    const int*   piw  = (const int*)d_in[2];

    float* out_patches = (float*)d_out;
    float* out_inds    = (float*)d_out + TOTAL_ELEMS;

    const int block = 256;
    const int grid  = BLOCKS_PER_SLICE * NXCD;   // 12,288 blocks
    cut_patches_kernel<<<grid, block, 0, stream>>>(imgs, pih, piw, out_patches, out_inds);
}

// Round 7
// 38.173 us; speedup vs baseline: 1.1918x; 1.1918x over previous
//
#include <hip/hip_runtime.h>

// Problem constants (match reference)
#define HH    128
#define WWID  128
#define CCH   3
#define PP    16
#define NIMG  64
#define NPROJ 512
#define NXCD  8
#define IMGS_PER_XCD (NIMG / NXCD)

#define TOTAL_ELEMS 25165824
#define SLICE_ELEMS (NPROJ * IMGS_PER_XCD * CCH * PP * PP)  // 3,145,728
// each thread covers 4 elems for TWO images (n, n+4) -> half-slice of vec4s
#define HALF_VEC4   (SLICE_ELEMS / 8)                       // 393,216
#define BLOCKS_PER_SLICE (HALF_VEC4 / 256)                  // 1,536

#define IMG_STRIDE4 (4 * CCH * HH * WWID)                   // 196,608 floats (n -> n+4)

typedef float f32x4 __attribute__((ext_vector_type(4)));

__global__ __launch_bounds__(256) void cut_patches_kernel(
    const float* __restrict__ imgs,
    const int*   __restrict__ pih,
    const int*   __restrict__ piw,
    float*       __restrict__ out_patches,
    float*       __restrict__ out_inds)
{
    int xcd = blockIdx.x & (NXCD - 1);
    int bid = blockIdx.x >> 3;
    int s   = bid * blockDim.x + threadIdx.x;   // 0 .. HALF_VEC4-1

    int e = s << 2;                 // element within half-slice [proj][nl4][c][ph][pw]
    // wave = 256 elems = one (proj, nl4, c) -> proj/w0/t wave-uniform
    int pw  = e & 15;               // multiple of 4
    int k4  = pw >> 2;
    int ph  = (e >> 4) & 15;
    int tmp = e >> 8;               // (proj, nl4, c)
    int c   = tmp % 3;
    tmp    /= 3;
    int nl4 = tmp & 3;              // images n=xcd*8+nl4 and n+4
    int proj = tmp >> 2;
    int n   = (xcd << 3) | nl4;

    // proj is wave-uniform -> force scalar loads for the position tables
    int projU = __builtin_amdgcn_readfirstlane(proj);
    int h0 = pih[projU];
    int w0 = piw[projU];

    int hh = h0 + ph;
    if (hh >= HH) hh -= HH;

    // base float index of image-n's row (multiple of 128 -> chunk-aligned)
    int base = hh * WWID + c * (HH * WWID) + n * (CCH * HH * WWID);
    const f32x4* rowv  = reinterpret_cast<const f32x4*>(imgs) + (base >> 2);
    const f32x4* rowv2 = rowv + (IMG_STRIDE4 / 4);          // image n+4, same row/chan

    int cb = (w0 >> 2) + k4;        // source chunk (pre-wrap)
    int t  = w0 & 3;                // wave-uniform misalignment

    // Aligned vec4 gathers + wave-uniform recombine (compile-time swizzles only).
    f32x4 A  = rowv [cb & 31];
    f32x4 A2 = rowv2[cb & 31];
    f32x4 v0, v1;
    if (t == 0) {
        v0 = A; v1 = A2;
    } else {
        f32x4 B  = rowv [(cb + 1) & 31];
        f32x4 B2 = rowv2[(cb + 1) & 31];
        if (t == 1) {
            v0 = (f32x4){A.y,  A.z,  A.w,  B.x };
            v1 = (f32x4){A2.y, A2.z, A2.w, B2.x};
        } else if (t == 2) {
            v0 = (f32x4){A.z,  A.w,  B.x,  B.y };
            v1 = (f32x4){A2.z, A2.w, B2.x, B2.y};
        } else {
            v0 = (f32x4){A.w,  B.x,  B.y,  B.z };
            v1 = (f32x4){A2.w, B2.x, B2.y, B2.z};
        }
    }

    // linear indices (exact in f32: lin < 2^24; +196608 stays < 2^24 exact)
    f32x4 i0, i1;
#pragma unroll
    for (int j = 0; j < 4; ++j) {
        int w = w0 + pw + j;
        if (w >= WWID) w -= WWID;
        float f = (float)(base + w);
        i0[j] = f;
        i1[j] = f + (float)IMG_STRIDE4;
    }

    // output vec index (global layout [proj][n][c][ph][pw]); n+4 is +768 vec4s
    int oelem = (((proj * NIMG + n) * CCH + c) << 8) | (ph << 4) | pw;
    int ovec  = oelem >> 2;
    int ovec2 = ovec + (IMG_STRIDE4 / 4) / 64;  // 4*3*256/4 = 768

    f32x4* op = reinterpret_cast<f32x4*>(out_patches);
    f32x4* oi = reinterpret_cast<f32x4*>(out_inds);
    op[ovec]  = v0;
    op[ovec2] = v1;
    oi[ovec]  = i0;
    oi[ovec2] = i1;
}

extern "C" void kernel_launch(void* const* d_in, const int* in_sizes, int n_in,
                              void* d_out, int out_size, void* d_ws, size_t ws_size,
                              hipStream_t stream) {
    const float* imgs = (const float*)d_in[0];
    const int*   pih  = (const int*)d_in[1];
    const int*   piw  = (const int*)d_in[2];

    float* out_patches = (float*)d_out;
    float* out_inds    = (float*)d_out + TOTAL_ELEMS;

    const int block = 256;
    const int grid  = BLOCKS_PER_SLICE * NXCD;   // 12,288 blocks
    cut_patches_kernel<<<grid, block, 0, stream>>>(imgs, pih, piw, out_patches, out_inds);
}